// Round 2
// baseline (5578.764 us; speedup 1.0000x reference)
//
#include <hip/hip_runtime.h>
#include <math.h>

#define N_NODES 50000
#define N_EDGES 800000
#define H 128
#define EIN 257
#define EPB 64   // edges per block

typedef short bf16x8 __attribute__((ext_vector_type(8)));
typedef short bf16x4 __attribute__((ext_vector_type(4)));
typedef float f32x4 __attribute__((ext_vector_type(4)));

// round-to-nearest-even f32 -> bf16 (finite inputs only)
static __device__ __forceinline__ short f2bf(float x) {
    unsigned u = __builtin_bit_cast(unsigned, x);
    unsigned r = (u + 0x7FFFu + ((u >> 16) & 1u)) >> 16;
    return (short)r;
}

static __device__ __forceinline__ float silu(float x) {
    return x / (1.0f + __expf(-x));
}

// ---- weight prep: f32 -> bf16, padded strides ----
#define P_W1  (128*264)
#define P_W2  (128*128)
#define P_TOT (P_W1 + P_W2 + P_W2 + P_W1 + P_W2)

__global__ __launch_bounds__(256) void prep_weights(
    const float* __restrict__ We1, const float* __restrict__ We2,
    const float* __restrict__ Wc1, const float* __restrict__ Wn1,
    const float* __restrict__ Wn2,
    short* __restrict__ W1b, short* __restrict__ W2b, short* __restrict__ Wc1b,
    short* __restrict__ Wn1b, short* __restrict__ Wn2b)
{
    int i = blockIdx.x * 256 + threadIdx.x;
    if (i >= P_TOT) return;
    if (i < P_W1) {
        int j = i / 264, k = i % 264;
        W1b[i] = (k < EIN) ? f2bf(We1[j * EIN + k]) : (short)0;
    } else if (i < P_W1 + P_W2) {
        int t = i - P_W1;
        W2b[t] = f2bf(We2[t]);
    } else if (i < P_W1 + 2 * P_W2) {
        int t = i - P_W1 - P_W2;
        Wc1b[t] = f2bf(Wc1[t]);
    } else if (i < P_W1 + 2 * P_W2 + P_W1) {
        int t = i - P_W1 - 2 * P_W2;
        int j = t / 264, k = t % 264;
        Wn1b[t] = (k < 256) ? f2bf(Wn1[j * 256 + k]) : (short)0;
    } else {
        int t = i - 2 * P_W1 - 2 * P_W2;
        Wn2b[t] = f2bf(Wn2[t]);
    }
}

// ---- edge kernel: 64 edges / block, 256 threads (4 waves) ----
// All agg/pos atomics issued AFTER the last barrier (no barrier drains them).
__global__ __launch_bounds__(256, 3) void edge_kernel(
    const float* __restrict__ h, const float* __restrict__ pos,
    const int* __restrict__ eidx,
    const float* __restrict__ We1f, const float* __restrict__ be1,
    const float* __restrict__ be2, const float* __restrict__ bc1,
    const float* __restrict__ wc2f, const float* __restrict__ bc2,
    const short* __restrict__ W1b, const short* __restrict__ W2b,
    const short* __restrict__ Wc1b,
    float* __restrict__ agg, float* __restrict__ pos_out)
{
    // s_m aliases s_ein: s_ein dead after GEMM1 MFMA reads (pre-barrier-2);
    // s_m first written after barrier 2.
    __shared__ union {
        short ein[EPB][264];   // 33792 B
        short m[EPB][136];     // 17408 B
    } s_u;
    __shared__ short s_t[EPB][136];
    __shared__ float s_rn[EPB];
    __shared__ float s_unit[EPB][3];
    __shared__ int   s_row[EPB];
    __shared__ float s_dot[EPB];

    const int tid = threadIdx.x;
    const int eb  = blockIdx.x * EPB;

    // head: per-edge geometry (wave 0; no one depends on it until barrier 1)
    if (tid < EPB) {
        int ge = eb + tid;
        int r = eidx[ge];
        int c = eidx[N_EDGES + ge];
        s_row[tid] = r;
        float dx = pos[r*3+0] - pos[c*3+0];
        float dy = pos[r*3+1] - pos[c*3+1];
        float dz = pos[r*3+2] - pos[c*3+2];
        float nrm = sqrtf(dx*dx + dy*dy + dz*dz);
        float rn  = fmaxf(nrm, 1e-8f);
        s_rn[tid] = rn;
        s_unit[tid][0] = dx / rn;
        s_unit[tid][1] = dy / rn;
        s_unit[tid][2] = dz / rn;
        s_dot[tid] = 0.0f;
    }

    // gather h[row]|h[col] -> s_ein (bf16); edge indices loaded directly
    {
        const int seg   = (tid >> 5) & 1;
        const int ebase = tid >> 6;          // 0..3
        const int o4    = tid & 31;
        const int ioff  = (seg ? N_EDGES : 0) + eb + ebase;
        int idxs[16];
        #pragma unroll
        for (int it = 0; it < 16; ++it)
            idxs[it] = eidx[ioff + it * 4];
        #pragma unroll
        for (int it = 0; it < 16; ++it) {
            float4 v = ((const float4*)h)[(size_t)idxs[it] * 32 + o4];
            bf16x4 s4 = { f2bf(v.x), f2bf(v.y), f2bf(v.z), f2bf(v.w) };
            *(bf16x4*)&s_u.ein[ebase + it * 4][seg * 128 + o4 * 4] = s4;
        }
    }
    __syncthreads();   // barrier 1

    const int lane = tid & 63;
    const int q    = lane >> 4;
    const int l15  = lane & 15;
    const int n0   = (tid >> 6) * 32;   // wave's 32 output columns

    // ---------------- GEMM1: [64x257] @ We1^T ----------------
    f32x4 acc[4][2] = {};
    #pragma unroll
    for (int ks = 0; ks < 8; ++ks) {
        int k0 = ks * 32 + q * 8;
        bf16x8 a0 = *(const bf16x8*)&s_u.ein[l15][k0];
        bf16x8 a1 = *(const bf16x8*)&s_u.ein[16 + l15][k0];
        bf16x8 a2 = *(const bf16x8*)&s_u.ein[32 + l15][k0];
        bf16x8 a3 = *(const bf16x8*)&s_u.ein[48 + l15][k0];
        bf16x8 b0 = *(const bf16x8*)&W1b[(n0 + l15) * 264 + k0];
        bf16x8 b1 = *(const bf16x8*)&W1b[(n0 + 16 + l15) * 264 + k0];
        acc[0][0] = __builtin_amdgcn_mfma_f32_16x16x32_bf16(a0, b0, acc[0][0], 0, 0, 0);
        acc[0][1] = __builtin_amdgcn_mfma_f32_16x16x32_bf16(a0, b1, acc[0][1], 0, 0, 0);
        acc[1][0] = __builtin_amdgcn_mfma_f32_16x16x32_bf16(a1, b0, acc[1][0], 0, 0, 0);
        acc[1][1] = __builtin_amdgcn_mfma_f32_16x16x32_bf16(a1, b1, acc[1][1], 0, 0, 0);
        acc[2][0] = __builtin_amdgcn_mfma_f32_16x16x32_bf16(a2, b0, acc[2][0], 0, 0, 0);
        acc[2][1] = __builtin_amdgcn_mfma_f32_16x16x32_bf16(a2, b1, acc[2][1], 0, 0, 0);
        acc[3][0] = __builtin_amdgcn_mfma_f32_16x16x32_bf16(a3, b0, acc[3][0], 0, 0, 0);
        acc[3][1] = __builtin_amdgcn_mfma_f32_16x16x32_bf16(a3, b1, acc[3][1], 0, 0, 0);
    }
    #pragma unroll
    for (int ct = 0; ct < 2; ++ct) {
        int col = n0 + ct * 16 + l15;
        float w256 = We1f[col * EIN + 256];   // rank-1 fixup for odd K
        float bias = be1[col];
        #pragma unroll
        for (int rt = 0; rt < 4; ++rt) {
            #pragma unroll
            for (int r = 0; r < 4; ++r) {
                int row = rt * 16 + q * 4 + r;
                float v = acc[rt][ct][r] + s_rn[row] * w256 + bias;
                s_t[row][col] = f2bf(silu(v));
            }
        }
    }
    __syncthreads();   // barrier 2

    // ---------------- GEMM2: t1 @ We2^T -> m ----------------
    f32x4 acc2[4][2] = {};
    #pragma unroll
    for (int ks = 0; ks < 4; ++ks) {
        int k0 = ks * 32 + q * 8;
        bf16x8 a0 = *(const bf16x8*)&s_t[l15][k0];
        bf16x8 a1 = *(const bf16x8*)&s_t[16 + l15][k0];
        bf16x8 a2 = *(const bf16x8*)&s_t[32 + l15][k0];
        bf16x8 a3 = *(const bf16x8*)&s_t[48 + l15][k0];
        bf16x8 b0 = *(const bf16x8*)&W2b[(n0 + l15) * 128 + k0];
        bf16x8 b1 = *(const bf16x8*)&W2b[(n0 + 16 + l15) * 128 + k0];
        acc2[0][0] = __builtin_amdgcn_mfma_f32_16x16x32_bf16(a0, b0, acc2[0][0], 0, 0, 0);
        acc2[0][1] = __builtin_amdgcn_mfma_f32_16x16x32_bf16(a0, b1, acc2[0][1], 0, 0, 0);
        acc2[1][0] = __builtin_amdgcn_mfma_f32_16x16x32_bf16(a1, b0, acc2[1][0], 0, 0, 0);
        acc2[1][1] = __builtin_amdgcn_mfma_f32_16x16x32_bf16(a1, b1, acc2[1][1], 0, 0, 0);
        acc2[2][0] = __builtin_amdgcn_mfma_f32_16x16x32_bf16(a2, b0, acc2[2][0], 0, 0, 0);
        acc2[2][1] = __builtin_amdgcn_mfma_f32_16x16x32_bf16(a2, b1, acc2[2][1], 0, 0, 0);
        acc2[3][0] = __builtin_amdgcn_mfma_f32_16x16x32_bf16(a3, b0, acc2[3][0], 0, 0, 0);
        acc2[3][1] = __builtin_amdgcn_mfma_f32_16x16x32_bf16(a3, b1, acc2[3][1], 0, 0, 0);
    }
    #pragma unroll
    for (int ct = 0; ct < 2; ++ct) {
        int col = n0 + ct * 16 + l15;
        float bias = be2[col];
        #pragma unroll
        for (int rt = 0; rt < 4; ++rt) {
            #pragma unroll
            for (int r = 0; r < 4; ++r) {
                int row = rt * 16 + q * 4 + r;
                s_u.m[row][col] = f2bf(acc2[rt][ct][r] + bias);   // no atomics here
            }
        }
    }
    __syncthreads();   // barrier 3

    // ---------------- GEMM3: m @ Wc1^T, dot wc2 ----------------
    f32x4 acc3[4][2] = {};
    #pragma unroll
    for (int ks = 0; ks < 4; ++ks) {
        int k0 = ks * 32 + q * 8;
        bf16x8 a0 = *(const bf16x8*)&s_u.m[l15][k0];
        bf16x8 a1 = *(const bf16x8*)&s_u.m[16 + l15][k0];
        bf16x8 a2 = *(const bf16x8*)&s_u.m[32 + l15][k0];
        bf16x8 a3 = *(const bf16x8*)&s_u.m[48 + l15][k0];
        bf16x8 b0 = *(const bf16x8*)&Wc1b[(n0 + l15) * 128 + k0];
        bf16x8 b1 = *(const bf16x8*)&Wc1b[(n0 + 16 + l15) * 128 + k0];
        acc3[0][0] = __builtin_amdgcn_mfma_f32_16x16x32_bf16(a0, b0, acc3[0][0], 0, 0, 0);
        acc3[0][1] = __builtin_amdgcn_mfma_f32_16x16x32_bf16(a0, b1, acc3[0][1], 0, 0, 0);
        acc3[1][0] = __builtin_amdgcn_mfma_f32_16x16x32_bf16(a1, b0, acc3[1][0], 0, 0, 0);
        acc3[1][1] = __builtin_amdgcn_mfma_f32_16x16x32_bf16(a1, b1, acc3[1][1], 0, 0, 0);
        acc3[2][0] = __builtin_amdgcn_mfma_f32_16x16x32_bf16(a2, b0, acc3[2][0], 0, 0, 0);
        acc3[2][1] = __builtin_amdgcn_mfma_f32_16x16x32_bf16(a2, b1, acc3[2][1], 0, 0, 0);
        acc3[3][0] = __builtin_amdgcn_mfma_f32_16x16x32_bf16(a3, b0, acc3[3][0], 0, 0, 0);
        acc3[3][1] = __builtin_amdgcn_mfma_f32_16x16x32_bf16(a3, b1, acc3[3][1], 0, 0, 0);
    }
    float p[4][4] = {};
    #pragma unroll
    for (int ct = 0; ct < 2; ++ct) {
        int col = n0 + ct * 16 + l15;
        float bias = bc1[col];
        float w2 = wc2f[col];
        #pragma unroll
        for (int rt = 0; rt < 4; ++rt) {
            #pragma unroll
            for (int r = 0; r < 4; ++r)
                p[rt][r] += silu(acc3[rt][ct][r] + bias) * w2;
        }
    }
    #pragma unroll
    for (int rt = 0; rt < 4; ++rt) {
        #pragma unroll
        for (int r = 0; r < 4; ++r) {
            float v = p[rt][r];
            v += __shfl_xor(v, 1);
            v += __shfl_xor(v, 2);
            v += __shfl_xor(v, 4);
            v += __shfl_xor(v, 8);
            if (l15 == 0) atomicAdd(&s_dot[rt * 16 + q * 4 + r], v);
        }
    }
    __syncthreads();   // barrier 4 (last)

    // ---- tail: all global atomics, nothing barriers on them ----
    if (tid < EPB) {
        float s = tanhf(s_dot[tid] + bc2[0]) * 0.1f;
        int r = s_row[tid];
        atomicAdd(&pos_out[r * 3 + 0], s * s_unit[tid][0]);
        atomicAdd(&pos_out[r * 3 + 1], s * s_unit[tid][1]);
        atomicAdd(&pos_out[r * 3 + 2], s * s_unit[tid][2]);
    }
    {
        const int r0 = tid >> 2;             // 0..63
        const int cg = (tid & 3) * 32;       // col group
        float* dst = &agg[(size_t)s_row[r0] * H + cg];
        const unsigned* src = (const unsigned*)&s_u.m[r0][cg];
        #pragma unroll
        for (int j = 0; j < 16; ++j) {
            unsigned pr = src[j];
            float f0 = __builtin_bit_cast(float, pr << 16);
            float f1 = __builtin_bit_cast(float, pr & 0xFFFF0000u);
            atomicAdd(dst + 2 * j,     f0);
            atomicAdd(dst + 2 * j + 1, f1);
        }
    }
}

// ---- node kernel: 32 nodes / block (unchanged; ~15% of runtime) ----
__global__ __launch_bounds__(256) void node_kernel(
    const float* __restrict__ h,
    const float* __restrict__ bn1, const float* __restrict__ bn2,
    const short* __restrict__ Wn1b, const short* __restrict__ Wn2b,
    float* __restrict__ hio)
{
    __shared__ short s_a[32][264];
    __shared__ short s_t[32][136];

    const int tid = threadIdx.x;
    const int nb  = blockIdx.x * 32;

    #pragma unroll
    for (int it = 0; it < 8; ++it) {
        int f   = tid + it * 256;
        int e   = f >> 6;
        int seg = (f >> 5) & 1;
        int o4  = f & 31;
        int node = nb + e;
        if (node >= N_NODES) node = N_NODES - 1;
        const float4* src = seg ? ((const float4*)hio + node * 32 + o4)
                                : ((const float4*)h   + node * 32 + o4);
        float4 v = *src;
        bf16x4 s4 = { f2bf(v.x), f2bf(v.y), f2bf(v.z), f2bf(v.w) };
        *(bf16x4*)&s_a[e][seg * 128 + o4 * 4] = s4;
    }
    __syncthreads();

    const int lane = tid & 63;
    const int q    = lane >> 4;
    const int l15  = lane & 15;
    const int n0   = (tid >> 6) * 32;

    f32x4 acc[2][2] = {};
    #pragma unroll
    for (int ks = 0; ks < 8; ++ks) {
        int k0 = ks * 32 + q * 8;
        bf16x8 a0 = *(const bf16x8*)&s_a[l15][k0];
        bf16x8 a1 = *(const bf16x8*)&s_a[16 + l15][k0];
        bf16x8 b0 = *(const bf16x8*)&Wn1b[(n0 + l15) * 264 + k0];
        bf16x8 b1 = *(const bf16x8*)&Wn1b[(n0 + 16 + l15) * 264 + k0];
        acc[0][0] = __builtin_amdgcn_mfma_f32_16x16x32_bf16(a0, b0, acc[0][0], 0, 0, 0);
        acc[0][1] = __builtin_amdgcn_mfma_f32_16x16x32_bf16(a0, b1, acc[0][1], 0, 0, 0);
        acc[1][0] = __builtin_amdgcn_mfma_f32_16x16x32_bf16(a1, b0, acc[1][0], 0, 0, 0);
        acc[1][1] = __builtin_amdgcn_mfma_f32_16x16x32_bf16(a1, b1, acc[1][1], 0, 0, 0);
    }
    #pragma unroll
    for (int ct = 0; ct < 2; ++ct) {
        int col = n0 + ct * 16 + l15;
        float bias = bn1[col];
        #pragma unroll
        for (int rt = 0; rt < 2; ++rt) {
            #pragma unroll
            for (int r = 0; r < 4; ++r) {
                int row = rt * 16 + q * 4 + r;
                s_t[row][col] = f2bf(silu(acc[rt][ct][r] + bias));
            }
        }
    }
    __syncthreads();

    f32x4 acc2[2][2] = {};
    #pragma unroll
    for (int ks = 0; ks < 4; ++ks) {
        int k0 = ks * 32 + q * 8;
        bf16x8 a0 = *(const bf16x8*)&s_t[l15][k0];
        bf16x8 a1 = *(const bf16x8*)&s_t[16 + l15][k0];
        bf16x8 b0 = *(const bf16x8*)&Wn2b[(n0 + l15) * 128 + k0];
        bf16x8 b1 = *(const bf16x8*)&Wn2b[(n0 + 16 + l15) * 128 + k0];
        acc2[0][0] = __builtin_amdgcn_mfma_f32_16x16x32_bf16(a0, b0, acc2[0][0], 0, 0, 0);
        acc2[0][1] = __builtin_amdgcn_mfma_f32_16x16x32_bf16(a0, b1, acc2[0][1], 0, 0, 0);
        acc2[1][0] = __builtin_amdgcn_mfma_f32_16x16x32_bf16(a1, b0, acc2[1][0], 0, 0, 0);
        acc2[1][1] = __builtin_amdgcn_mfma_f32_16x16x32_bf16(a1, b1, acc2[1][1], 0, 0, 0);
    }
    #pragma unroll
    for (int ct = 0; ct < 2; ++ct) {
        int col = n0 + ct * 16 + l15;
        float bias = bn2[col];
        #pragma unroll
        for (int rt = 0; rt < 2; ++rt) {
            #pragma unroll
            for (int r = 0; r < 4; ++r) {
                int row = rt * 16 + q * 4 + r;
                int nrow = nb + row;
                if (nrow < N_NODES) {
                    float v = acc2[rt][ct][r] + bias + h[(size_t)nrow * H + col];
                    hio[(size_t)nrow * H + col] = v;
                }
            }
        }
    }
}

extern "C" void kernel_launch(void* const* d_in, const int* in_sizes, int n_in,
                              void* d_out, int out_size, void* d_ws, size_t ws_size,
                              hipStream_t stream) {
    const float* h   = (const float*)d_in[0];
    const float* pos = (const float*)d_in[1];
    const int*  eidx = (const int*)d_in[2];
    const float* We1 = (const float*)d_in[3];
    const float* be1 = (const float*)d_in[4];
    const float* We2 = (const float*)d_in[5];
    const float* be2 = (const float*)d_in[6];
    const float* Wn1 = (const float*)d_in[7];
    const float* bn1 = (const float*)d_in[8];
    const float* Wn2 = (const float*)d_in[9];
    const float* bn2 = (const float*)d_in[10];
    const float* Wc1 = (const float*)d_in[11];
    const float* bc1 = (const float*)d_in[12];
    const float* Wc2 = (const float*)d_in[13];
    const float* bc2 = (const float*)d_in[14];

    float* out_h   = (float*)d_out;                      // doubles as agg
    float* out_pos = out_h + (size_t)N_NODES * H;

    char* ws = (char*)d_ws;
    short* W1b  = (short*)(ws);
    short* W2b  = (short*)(ws + 2 * P_W1);
    short* Wc1b = (short*)(ws + 2 * (P_W1 + P_W2));
    short* Wn1b = (short*)(ws + 2 * (P_W1 + 2 * P_W2));
    short* Wn2b = (short*)(ws + 2 * (2 * P_W1 + 2 * P_W2));

    hipMemsetAsync(out_h, 0, (size_t)N_NODES * H * sizeof(float), stream);
    hipMemcpyAsync(out_pos, pos, (size_t)N_NODES * 3 * sizeof(float),
                   hipMemcpyDeviceToDevice, stream);

    prep_weights<<<(P_TOT + 255) / 256, 256, 0, stream>>>(
        We1, We2, Wc1, Wn1, Wn2, W1b, W2b, Wc1b, Wn1b, Wn2b);

    edge_kernel<<<N_EDGES / EPB, 256, 0, stream>>>(
        h, pos, eidx, We1, be1, be2, bc1, Wc2, bc2,
        W1b, W2b, Wc1b, out_h, out_pos);

    node_kernel<<<(N_NODES + 31) / 32, 256, 0, stream>>>(
        h, bn1, bn2, Wn1b, Wn2b, out_h);
}

// Round 3
// 483.190 us; speedup vs baseline: 11.5457x; 11.5457x over previous
//
#include <hip/hip_runtime.h>
#include <math.h>

#define N_NODES 50000
#define N_EDGES 800000
#define H 128
#define EIN 257
#define EPB 64   // edges per block

typedef short bf16x8 __attribute__((ext_vector_type(8)));
typedef short bf16x4 __attribute__((ext_vector_type(4)));
typedef short bf16x2 __attribute__((ext_vector_type(2)));
typedef float f32x4 __attribute__((ext_vector_type(4)));

// round-to-nearest-even f32 -> bf16 (finite inputs only)
static __device__ __forceinline__ short f2bf(float x) {
    unsigned u = __builtin_bit_cast(unsigned, x);
    unsigned r = (u + 0x7FFFu + ((u >> 16) & 1u)) >> 16;
    return (short)r;
}

static __device__ __forceinline__ float silu(float x) {
    return x / (1.0f + __expf(-x));
}

// packed bf16 atomic add (global_atomic_pk_add_bf16). addr 4B-aligned,
// val = two bf16 in one dword (low short = even col).
static __device__ __forceinline__ void pk_agg_add(unsigned* addr, unsigned val) {
#if __has_builtin(__builtin_amdgcn_global_atomic_fadd_v2bf16)
    bf16x2 v = __builtin_bit_cast(bf16x2, val);
    (void)__builtin_amdgcn_global_atomic_fadd_v2bf16(
        (__attribute__((address_space(1))) bf16x2*)(unsigned long long)addr, v);
#else
    asm volatile("global_atomic_pk_add_bf16 %0, %1, off"
                 :: "v"(addr), "v"(val) : "memory");
#endif
}

// ---- weight prep: f32 -> bf16, padded strides ----
#define P_W1  (128*264)
#define P_W2  (128*128)
#define P_TOT (P_W1 + P_W2 + P_W2 + P_W1 + P_W2)

__global__ __launch_bounds__(256) void prep_weights(
    const float* __restrict__ We1, const float* __restrict__ We2,
    const float* __restrict__ Wc1, const float* __restrict__ Wn1,
    const float* __restrict__ Wn2,
    short* __restrict__ W1b, short* __restrict__ W2b, short* __restrict__ Wc1b,
    short* __restrict__ Wn1b, short* __restrict__ Wn2b)
{
    int i = blockIdx.x * 256 + threadIdx.x;
    if (i >= P_TOT) return;
    if (i < P_W1) {
        int j = i / 264, k = i % 264;
        W1b[i] = (k < EIN) ? f2bf(We1[j * EIN + k]) : (short)0;
    } else if (i < P_W1 + P_W2) {
        int t = i - P_W1;
        W2b[t] = f2bf(We2[t]);
    } else if (i < P_W1 + 2 * P_W2) {
        int t = i - P_W1 - P_W2;
        Wc1b[t] = f2bf(Wc1[t]);
    } else if (i < P_W1 + 2 * P_W2 + P_W1) {
        int t = i - P_W1 - 2 * P_W2;
        int j = t / 264, k = t % 264;
        Wn1b[t] = (k < 256) ? f2bf(Wn1[j * 256 + k]) : (short)0;
    } else {
        int t = i - 2 * P_W1 - 2 * P_W2;
        Wn2b[t] = f2bf(Wn2[t]);
    }
}

// ---- edge kernel: 64 edges / block, 256 threads (4 waves) ----
// Agg atomics: wave-per-row, lane l -> cols {2l,2l+1}: 256B contiguous per
// wave instruction (round-2's scatter pattern was the 10x regression).
template<bool AGGBF16>
__global__ __launch_bounds__(256, 3) void edge_kernel(
    const float* __restrict__ h, const float* __restrict__ pos,
    const int* __restrict__ eidx,
    const float* __restrict__ We1f, const float* __restrict__ be1,
    const float* __restrict__ be2, const float* __restrict__ bc1,
    const float* __restrict__ wc2f, const float* __restrict__ bc2,
    const short* __restrict__ W1b, const short* __restrict__ W2b,
    const short* __restrict__ Wc1b,
    unsigned* __restrict__ aggb,   // bf16 agg, 64 dwords/row (AGGBF16)
    float* __restrict__ aggf,      // f32 agg (fallback)
    float* __restrict__ pos_out)
{
    __shared__ union {
        short ein[EPB][264];   // 33792 B
        short m[EPB][136];     // 17408 B (ein dead after GEMM1 reads)
    } s_u;
    __shared__ short s_t[EPB][136];
    __shared__ float s_rn[EPB];
    __shared__ float s_unit[EPB][3];
    __shared__ int   s_row[EPB];
    __shared__ float s_dot[EPB];

    const int tid = threadIdx.x;
    const int eb  = blockIdx.x * EPB;

    if (tid < EPB) {
        int ge = eb + tid;
        int r = eidx[ge];
        int c = eidx[N_EDGES + ge];
        s_row[tid] = r;
        float dx = pos[r*3+0] - pos[c*3+0];
        float dy = pos[r*3+1] - pos[c*3+1];
        float dz = pos[r*3+2] - pos[c*3+2];
        float nrm = sqrtf(dx*dx + dy*dy + dz*dz);
        float rn  = fmaxf(nrm, 1e-8f);
        s_rn[tid] = rn;
        s_unit[tid][0] = dx / rn;
        s_unit[tid][1] = dy / rn;
        s_unit[tid][2] = dz / rn;
        s_dot[tid] = 0.0f;
    }

    // gather h[row]|h[col] -> s_ein (bf16)
    {
        const int seg   = (tid >> 5) & 1;
        const int ebase = tid >> 6;
        const int o4    = tid & 31;
        const int ioff  = (seg ? N_EDGES : 0) + eb + ebase;
        int idxs[16];
        #pragma unroll
        for (int it = 0; it < 16; ++it)
            idxs[it] = eidx[ioff + it * 4];
        #pragma unroll
        for (int it = 0; it < 16; ++it) {
            float4 v = ((const float4*)h)[(size_t)idxs[it] * 32 + o4];
            bf16x4 s4 = { f2bf(v.x), f2bf(v.y), f2bf(v.z), f2bf(v.w) };
            *(bf16x4*)&s_u.ein[ebase + it * 4][seg * 128 + o4 * 4] = s4;
        }
    }
    __syncthreads();   // barrier 1

    const int lane = tid & 63;
    const int q    = lane >> 4;
    const int l15  = lane & 15;
    const int n0   = (tid >> 6) * 32;
    const int w    = tid >> 6;

    // ---------------- GEMM1: [64x257] @ We1^T ----------------
    f32x4 acc[4][2] = {};
    #pragma unroll
    for (int ks = 0; ks < 8; ++ks) {
        int k0 = ks * 32 + q * 8;
        bf16x8 a0 = *(const bf16x8*)&s_u.ein[l15][k0];
        bf16x8 a1 = *(const bf16x8*)&s_u.ein[16 + l15][k0];
        bf16x8 a2 = *(const bf16x8*)&s_u.ein[32 + l15][k0];
        bf16x8 a3 = *(const bf16x8*)&s_u.ein[48 + l15][k0];
        bf16x8 b0 = *(const bf16x8*)&W1b[(n0 + l15) * 264 + k0];
        bf16x8 b1 = *(const bf16x8*)&W1b[(n0 + 16 + l15) * 264 + k0];
        acc[0][0] = __builtin_amdgcn_mfma_f32_16x16x32_bf16(a0, b0, acc[0][0], 0, 0, 0);
        acc[0][1] = __builtin_amdgcn_mfma_f32_16x16x32_bf16(a0, b1, acc[0][1], 0, 0, 0);
        acc[1][0] = __builtin_amdgcn_mfma_f32_16x16x32_bf16(a1, b0, acc[1][0], 0, 0, 0);
        acc[1][1] = __builtin_amdgcn_mfma_f32_16x16x32_bf16(a1, b1, acc[1][1], 0, 0, 0);
        acc[2][0] = __builtin_amdgcn_mfma_f32_16x16x32_bf16(a2, b0, acc[2][0], 0, 0, 0);
        acc[2][1] = __builtin_amdgcn_mfma_f32_16x16x32_bf16(a2, b1, acc[2][1], 0, 0, 0);
        acc[3][0] = __builtin_amdgcn_mfma_f32_16x16x32_bf16(a3, b0, acc[3][0], 0, 0, 0);
        acc[3][1] = __builtin_amdgcn_mfma_f32_16x16x32_bf16(a3, b1, acc[3][1], 0, 0, 0);
    }
    #pragma unroll
    for (int ct = 0; ct < 2; ++ct) {
        int col = n0 + ct * 16 + l15;
        float w256 = We1f[col * EIN + 256];   // rank-1 fixup for odd K
        float bias = be1[col];
        #pragma unroll
        for (int rt = 0; rt < 4; ++rt) {
            #pragma unroll
            for (int r = 0; r < 4; ++r) {
                int row = rt * 16 + q * 4 + r;
                float v = acc[rt][ct][r] + s_rn[row] * w256 + bias;
                s_t[row][col] = f2bf(silu(v));
            }
        }
    }
    __syncthreads();   // barrier 2

    // ---------------- GEMM2: t1 @ We2^T -> m ----------------
    f32x4 acc2[4][2] = {};
    #pragma unroll
    for (int ks = 0; ks < 4; ++ks) {
        int k0 = ks * 32 + q * 8;
        bf16x8 a0 = *(const bf16x8*)&s_t[l15][k0];
        bf16x8 a1 = *(const bf16x8*)&s_t[16 + l15][k0];
        bf16x8 a2 = *(const bf16x8*)&s_t[32 + l15][k0];
        bf16x8 a3 = *(const bf16x8*)&s_t[48 + l15][k0];
        bf16x8 b0 = *(const bf16x8*)&W2b[(n0 + l15) * 128 + k0];
        bf16x8 b1 = *(const bf16x8*)&W2b[(n0 + 16 + l15) * 128 + k0];
        acc2[0][0] = __builtin_amdgcn_mfma_f32_16x16x32_bf16(a0, b0, acc2[0][0], 0, 0, 0);
        acc2[0][1] = __builtin_amdgcn_mfma_f32_16x16x32_bf16(a0, b1, acc2[0][1], 0, 0, 0);
        acc2[1][0] = __builtin_amdgcn_mfma_f32_16x16x32_bf16(a1, b0, acc2[1][0], 0, 0, 0);
        acc2[1][1] = __builtin_amdgcn_mfma_f32_16x16x32_bf16(a1, b1, acc2[1][1], 0, 0, 0);
        acc2[2][0] = __builtin_amdgcn_mfma_f32_16x16x32_bf16(a2, b0, acc2[2][0], 0, 0, 0);
        acc2[2][1] = __builtin_amdgcn_mfma_f32_16x16x32_bf16(a2, b1, acc2[2][1], 0, 0, 0);
        acc2[3][0] = __builtin_amdgcn_mfma_f32_16x16x32_bf16(a3, b0, acc2[3][0], 0, 0, 0);
        acc2[3][1] = __builtin_amdgcn_mfma_f32_16x16x32_bf16(a3, b1, acc2[3][1], 0, 0, 0);
    }
    #pragma unroll
    for (int ct = 0; ct < 2; ++ct) {
        int col = n0 + ct * 16 + l15;
        float bias = be2[col];
        #pragma unroll
        for (int rt = 0; rt < 4; ++rt) {
            #pragma unroll
            for (int r = 0; r < 4; ++r) {
                int row = rt * 16 + q * 4 + r;
                s_u.m[row][col] = f2bf(acc2[rt][ct][r] + bias);
            }
        }
    }
    __syncthreads();   // barrier 3

    // ---- agg atomics: wave-per-row, coalesced, fire-and-forget ----
    // lane l reads the dword (2 bf16) at s_m[row][2l]; wave instruction
    // covers one full agg row = 256B contiguous. Overlaps GEMM3.
    #pragma unroll
    for (int i = 0; i < 16; ++i) {
        int row = w + i * 4;
        unsigned pr = *(const unsigned*)&s_u.m[row][lane * 2];
        if constexpr (AGGBF16) {
            pk_agg_add(&aggb[(size_t)s_row[row] * 64 + lane], pr);
        } else {
            float f0 = __builtin_bit_cast(float, pr << 16);
            float f1 = __builtin_bit_cast(float, pr & 0xFFFF0000u);
            float* dst = &aggf[(size_t)s_row[row] * H + 2 * lane];
            atomicAdd(dst, f0);
            atomicAdd(dst + 1, f1);
        }
    }

    // ---------------- GEMM3: m @ Wc1^T, dot wc2 ----------------
    f32x4 acc3[4][2] = {};
    #pragma unroll
    for (int ks = 0; ks < 4; ++ks) {
        int k0 = ks * 32 + q * 8;
        bf16x8 a0 = *(const bf16x8*)&s_u.m[l15][k0];
        bf16x8 a1 = *(const bf16x8*)&s_u.m[16 + l15][k0];
        bf16x8 a2 = *(const bf16x8*)&s_u.m[32 + l15][k0];
        bf16x8 a3 = *(const bf16x8*)&s_u.m[48 + l15][k0];
        bf16x8 b0 = *(const bf16x8*)&Wc1b[(n0 + l15) * 128 + k0];
        bf16x8 b1 = *(const bf16x8*)&Wc1b[(n0 + 16 + l15) * 128 + k0];
        acc3[0][0] = __builtin_amdgcn_mfma_f32_16x16x32_bf16(a0, b0, acc3[0][0], 0, 0, 0);
        acc3[0][1] = __builtin_amdgcn_mfma_f32_16x16x32_bf16(a0, b1, acc3[0][1], 0, 0, 0);
        acc3[1][0] = __builtin_amdgcn_mfma_f32_16x16x32_bf16(a1, b0, acc3[1][0], 0, 0, 0);
        acc3[1][1] = __builtin_amdgcn_mfma_f32_16x16x32_bf16(a1, b1, acc3[1][1], 0, 0, 0);
        acc3[2][0] = __builtin_amdgcn_mfma_f32_16x16x32_bf16(a2, b0, acc3[2][0], 0, 0, 0);
        acc3[2][1] = __builtin_amdgcn_mfma_f32_16x16x32_bf16(a2, b1, acc3[2][1], 0, 0, 0);
        acc3[3][0] = __builtin_amdgcn_mfma_f32_16x16x32_bf16(a3, b0, acc3[3][0], 0, 0, 0);
        acc3[3][1] = __builtin_amdgcn_mfma_f32_16x16x32_bf16(a3, b1, acc3[3][1], 0, 0, 0);
    }
    float p[4][4] = {};
    #pragma unroll
    for (int ct = 0; ct < 2; ++ct) {
        int col = n0 + ct * 16 + l15;
        float bias = bc1[col];
        float w2 = wc2f[col];
        #pragma unroll
        for (int rt = 0; rt < 4; ++rt) {
            #pragma unroll
            for (int r = 0; r < 4; ++r)
                p[rt][r] += silu(acc3[rt][ct][r] + bias) * w2;
        }
    }
    #pragma unroll
    for (int rt = 0; rt < 4; ++rt) {
        #pragma unroll
        for (int r = 0; r < 4; ++r) {
            float v = p[rt][r];
            v += __shfl_xor(v, 1);
            v += __shfl_xor(v, 2);
            v += __shfl_xor(v, 4);
            v += __shfl_xor(v, 8);
            if (l15 == 0) atomicAdd(&s_dot[rt * 16 + q * 4 + r], v);
        }
    }
    __syncthreads();   // barrier 4

    if (tid < EPB) {
        float s = tanhf(s_dot[tid] + bc2[0]) * 0.1f;
        int r = s_row[tid];
        atomicAdd(&pos_out[r * 3 + 0], s * s_unit[tid][0]);
        atomicAdd(&pos_out[r * 3 + 1], s * s_unit[tid][1]);
        atomicAdd(&pos_out[r * 3 + 2], s * s_unit[tid][2]);
    }
}

// ---- node kernel: 32 nodes / block ----
template<bool AGGBF16>
__global__ __launch_bounds__(256) void node_kernel(
    const float* __restrict__ h,
    const unsigned short* __restrict__ aggb, const float* __restrict__ aggf,
    const float* __restrict__ bn1, const float* __restrict__ bn2,
    const short* __restrict__ Wn1b, const short* __restrict__ Wn2b,
    float* __restrict__ hout)
{
    __shared__ short s_a[32][264];
    __shared__ short s_t[32][136];

    const int tid = threadIdx.x;
    const int nb  = blockIdx.x * 32;

    #pragma unroll
    for (int it = 0; it < 8; ++it) {
        int f   = tid + it * 256;
        int e   = f >> 6;
        int seg = (f >> 5) & 1;
        int o4  = f & 31;
        int node = nb + e;
        if (node >= N_NODES) node = N_NODES - 1;
        if (seg == 0) {
            float4 v = ((const float4*)h)[(size_t)node * 32 + o4];
            bf16x4 s4 = { f2bf(v.x), f2bf(v.y), f2bf(v.z), f2bf(v.w) };
            *(bf16x4*)&s_a[e][o4 * 4] = s4;
        } else if constexpr (AGGBF16) {
            ushort4 v = ((const ushort4*)aggb)[(size_t)node * 32 + o4];
            *(ushort4*)&s_a[e][128 + o4 * 4] = v;
        } else {
            float4 v = ((const float4*)aggf)[(size_t)node * 32 + o4];
            bf16x4 s4 = { f2bf(v.x), f2bf(v.y), f2bf(v.z), f2bf(v.w) };
            *(bf16x4*)&s_a[e][128 + o4 * 4] = s4;
        }
    }
    __syncthreads();

    const int lane = tid & 63;
    const int q    = lane >> 4;
    const int l15  = lane & 15;
    const int n0   = (tid >> 6) * 32;

    f32x4 acc[2][2] = {};
    #pragma unroll
    for (int ks = 0; ks < 8; ++ks) {
        int k0 = ks * 32 + q * 8;
        bf16x8 a0 = *(const bf16x8*)&s_a[l15][k0];
        bf16x8 a1 = *(const bf16x8*)&s_a[16 + l15][k0];
        bf16x8 b0 = *(const bf16x8*)&Wn1b[(n0 + l15) * 264 + k0];
        bf16x8 b1 = *(const bf16x8*)&Wn1b[(n0 + 16 + l15) * 264 + k0];
        acc[0][0] = __builtin_amdgcn_mfma_f32_16x16x32_bf16(a0, b0, acc[0][0], 0, 0, 0);
        acc[0][1] = __builtin_amdgcn_mfma_f32_16x16x32_bf16(a0, b1, acc[0][1], 0, 0, 0);
        acc[1][0] = __builtin_amdgcn_mfma_f32_16x16x32_bf16(a1, b0, acc[1][0], 0, 0, 0);
        acc[1][1] = __builtin_amdgcn_mfma_f32_16x16x32_bf16(a1, b1, acc[1][1], 0, 0, 0);
    }
    #pragma unroll
    for (int ct = 0; ct < 2; ++ct) {
        int col = n0 + ct * 16 + l15;
        float bias = bn1[col];
        #pragma unroll
        for (int rt = 0; rt < 2; ++rt) {
            #pragma unroll
            for (int r = 0; r < 4; ++r) {
                int row = rt * 16 + q * 4 + r;
                s_t[row][col] = f2bf(silu(acc[rt][ct][r] + bias));
            }
        }
    }
    __syncthreads();

    f32x4 acc2[2][2] = {};
    #pragma unroll
    for (int ks = 0; ks < 4; ++ks) {
        int k0 = ks * 32 + q * 8;
        bf16x8 a0 = *(const bf16x8*)&s_t[l15][k0];
        bf16x8 a1 = *(const bf16x8*)&s_t[16 + l15][k0];
        bf16x8 b0 = *(const bf16x8*)&Wn2b[(n0 + l15) * 128 + k0];
        bf16x8 b1 = *(const bf16x8*)&Wn2b[(n0 + 16 + l15) * 128 + k0];
        acc2[0][0] = __builtin_amdgcn_mfma_f32_16x16x32_bf16(a0, b0, acc2[0][0], 0, 0, 0);
        acc2[0][1] = __builtin_amdgcn_mfma_f32_16x16x32_bf16(a0, b1, acc2[0][1], 0, 0, 0);
        acc2[1][0] = __builtin_amdgcn_mfma_f32_16x16x32_bf16(a1, b0, acc2[1][0], 0, 0, 0);
        acc2[1][1] = __builtin_amdgcn_mfma_f32_16x16x32_bf16(a1, b1, acc2[1][1], 0, 0, 0);
    }
    #pragma unroll
    for (int ct = 0; ct < 2; ++ct) {
        int col = n0 + ct * 16 + l15;
        float bias = bn2[col];
        #pragma unroll
        for (int rt = 0; rt < 2; ++rt) {
            #pragma unroll
            for (int r = 0; r < 4; ++r) {
                int row = rt * 16 + q * 4 + r;
                int nrow = nb + row;
                if (nrow < N_NODES) {
                    float v = acc2[rt][ct][r] + bias + h[(size_t)nrow * H + col];
                    hout[(size_t)nrow * H + col] = v;
                }
            }
        }
    }
}

extern "C" void kernel_launch(void* const* d_in, const int* in_sizes, int n_in,
                              void* d_out, int out_size, void* d_ws, size_t ws_size,
                              hipStream_t stream) {
    const float* h   = (const float*)d_in[0];
    const float* pos = (const float*)d_in[1];
    const int*  eidx = (const int*)d_in[2];
    const float* We1 = (const float*)d_in[3];
    const float* be1 = (const float*)d_in[4];
    const float* We2 = (const float*)d_in[5];
    const float* be2 = (const float*)d_in[6];
    const float* Wn1 = (const float*)d_in[7];
    const float* bn1 = (const float*)d_in[8];
    const float* Wn2 = (const float*)d_in[9];
    const float* bn2 = (const float*)d_in[10];
    const float* Wc1 = (const float*)d_in[11];
    const float* bc1 = (const float*)d_in[12];
    const float* Wc2 = (const float*)d_in[13];
    const float* bc2 = (const float*)d_in[14];

    float* out_h   = (float*)d_out;
    float* out_pos = out_h + (size_t)N_NODES * H;

    char* ws = (char*)d_ws;
    short* W1b  = (short*)(ws);
    short* W2b  = (short*)(ws + 2 * P_W1);
    short* Wc1b = (short*)(ws + 2 * (P_W1 + P_W2));
    short* Wn1b = (short*)(ws + 2 * (P_W1 + 2 * P_W2));
    short* Wn2b = (short*)(ws + 2 * (2 * P_W1 + 2 * P_W2));
    const size_t WSW = 2 * (size_t)(2 * P_W1 + 3 * P_W2);   // 233472 B
    const size_t AGG_BYTES = (size_t)N_NODES * H * 2;       // 12.8 MB
    const bool use_bf16 = (ws_size >= WSW + AGG_BYTES);

    hipMemcpyAsync(out_pos, pos, (size_t)N_NODES * 3 * sizeof(float),
                   hipMemcpyDeviceToDevice, stream);
    prep_weights<<<(P_TOT + 255) / 256, 256, 0, stream>>>(
        We1, We2, Wc1, Wn1, Wn2, W1b, W2b, Wc1b, Wn1b, Wn2b);

    if (use_bf16) {
        unsigned* aggb = (unsigned*)(ws + WSW);
        hipMemsetAsync(aggb, 0, AGG_BYTES, stream);   // 0x0000 == bf16 +0.0
        edge_kernel<true><<<N_EDGES / EPB, 256, 0, stream>>>(
            h, pos, eidx, We1, be1, be2, bc1, Wc2, bc2,
            W1b, W2b, Wc1b, aggb, nullptr, out_pos);
        node_kernel<true><<<(N_NODES + 31) / 32, 256, 0, stream>>>(
            h, (const unsigned short*)aggb, nullptr, bn1, bn2, Wn1b, Wn2b, out_h);
    } else {
        // fallback: f32 agg in d_out h region (overwritten by node_kernel)
        hipMemsetAsync(out_h, 0, (size_t)N_NODES * H * sizeof(float), stream);
        edge_kernel<false><<<N_EDGES / EPB, 256, 0, stream>>>(
            h, pos, eidx, We1, be1, be2, bc1, Wc2, bc2,
            W1b, W2b, Wc1b, nullptr, out_h, out_pos);
        node_kernel<false><<<(N_NODES + 31) / 32, 256, 0, stream>>>(
            h, nullptr, out_h, bn1, bn2, Wn1b, Wn2b, out_h);
    }
}

// Round 4
// 464.906 us; speedup vs baseline: 11.9998x; 1.0393x over previous
//
#include <hip/hip_runtime.h>
#include <math.h>

#define N_NODES 50000
#define N_EDGES 800000
#define H 128
#define EIN 257
#define EPB 64   // edges per block

typedef short bf16x8 __attribute__((ext_vector_type(8)));
typedef short bf16x4 __attribute__((ext_vector_type(4)));
typedef short bf16x2 __attribute__((ext_vector_type(2)));
typedef float f32x4 __attribute__((ext_vector_type(4)));

// round-to-nearest-even f32 -> bf16 (one-time prep conversions)
static __device__ __forceinline__ short f2bf(float x) {
    unsigned u = __builtin_bit_cast(unsigned, x);
    unsigned r = (u + 0x7FFFu + ((u >> 16) & 1u)) >> 16;
    return (short)r;
}

// cheap round-half-up f32 -> bf16 (2 VALU insts; differs from RNE only at ties)
static __device__ __forceinline__ short f2bfr(float x) {
    return (short)((__builtin_bit_cast(unsigned, x) + 0x8000u) >> 16);
}

// fast silu: avoids precise-division sequence (~10 insts -> ~4)
static __device__ __forceinline__ float silu(float x) {
#if __has_builtin(__builtin_amdgcn_rcpf)
    return x * __builtin_amdgcn_rcpf(1.0f + __expf(-x));
#else
    return x / (1.0f + __expf(-x));
#endif
}

// packed bf16 atomic add
static __device__ __forceinline__ void pk_agg_add(unsigned* addr, unsigned val) {
#if __has_builtin(__builtin_amdgcn_global_atomic_fadd_v2bf16)
    bf16x2 v = __builtin_bit_cast(bf16x2, val);
    (void)__builtin_amdgcn_global_atomic_fadd_v2bf16(
        (__attribute__((address_space(1))) bf16x2*)(unsigned long long)addr, v);
#else
    asm volatile("global_atomic_pk_add_bf16 %0, %1, off"
                 :: "v"(addr), "v"(val) : "memory");
#endif
}

// ---- prep: weights f32->bf16 (padded) + h f32->bf16 ----
#define P_W1  (128*264)
#define P_W2  (128*128)
#define P_TOT (P_W1 + P_W2 + P_W2 + P_W1 + P_W2)
#define NH4   (N_NODES * H / 4)          // h elements / 4 (float4 per thread)

__global__ __launch_bounds__(256) void prep_all(
    const float* __restrict__ hf,
    const float* __restrict__ We1, const float* __restrict__ We2,
    const float* __restrict__ Wc1, const float* __restrict__ Wn1,
    const float* __restrict__ Wn2,
    short* __restrict__ hbf,
    short* __restrict__ W1b, short* __restrict__ W2b, short* __restrict__ Wc1b,
    short* __restrict__ Wn1b, short* __restrict__ Wn2b)
{
    int i = blockIdx.x * 256 + threadIdx.x;
    if (i < NH4) {
        float4 v = ((const float4*)hf)[i];
        bf16x4 s4 = { f2bf(v.x), f2bf(v.y), f2bf(v.z), f2bf(v.w) };
        *(bf16x4*)&hbf[i * 4] = s4;
        return;
    }
    i -= NH4;
    if (i >= P_TOT) return;
    if (i < P_W1) {
        int j = i / 264, k = i % 264;
        W1b[i] = (k < EIN) ? f2bf(We1[j * EIN + k]) : (short)0;
    } else if (i < P_W1 + P_W2) {
        int t = i - P_W1;
        W2b[t] = f2bf(We2[t]);
    } else if (i < P_W1 + 2 * P_W2) {
        int t = i - P_W1 - P_W2;
        Wc1b[t] = f2bf(Wc1[t]);
    } else if (i < P_W1 + 2 * P_W2 + P_W1) {
        int t = i - P_W1 - 2 * P_W2;
        int j = t / 264, k = t % 264;
        Wn1b[t] = (k < 256) ? f2bf(Wn1[j * 256 + k]) : (short)0;
    } else {
        int t = i - 2 * P_W1 - 2 * P_W2;
        Wn2b[t] = f2bf(Wn2[t]);
    }
}

// ---- edge kernel: 64 edges / block, 256 threads (4 waves) ----
template<bool AGGBF16>
__global__ __launch_bounds__(256, 3) void edge_kernel(
    const short* __restrict__ hbf, const float* __restrict__ pos,
    const int* __restrict__ eidx,
    const float* __restrict__ We1f, const float* __restrict__ be1,
    const float* __restrict__ be2, const float* __restrict__ bc1,
    const float* __restrict__ wc2f, const float* __restrict__ bc2,
    const short* __restrict__ W1b, const short* __restrict__ W2b,
    const short* __restrict__ Wc1b,
    unsigned* __restrict__ aggb,   // bf16 agg, 64 dwords/row
    float* __restrict__ aggf,      // f32 agg (fallback)
    float* __restrict__ pos_out)
{
    __shared__ union {
        short ein[EPB][264];   // 33792 B
        short m[EPB][136];     // (ein dead after GEMM1 reads)
    } s_u;
    __shared__ short s_t[EPB][136];
    __shared__ float s_rn[EPB];
    __shared__ float s_unit[EPB][3];
    __shared__ int   s_row[EPB];
    __shared__ float s_dot[EPB];

    const int tid = threadIdx.x;
    const int eb  = blockIdx.x * EPB;

    if (tid < EPB) {
        int ge = eb + tid;
        int r = eidx[ge];
        int c = eidx[N_EDGES + ge];
        s_row[tid] = r;
        float dx = pos[r*3+0] - pos[c*3+0];
        float dy = pos[r*3+1] - pos[c*3+1];
        float dz = pos[r*3+2] - pos[c*3+2];
        float nrm = sqrtf(dx*dx + dy*dy + dz*dz);
        float rn  = fmaxf(nrm, 1e-8f);
        s_rn[tid] = rn;
        s_unit[tid][0] = dx / rn;
        s_unit[tid][1] = dy / rn;
        s_unit[tid][2] = dz / rn;
        s_dot[tid] = 0.0f;
    }

    // gather hbf[row]|hbf[col] -> s_ein: pure bf16 16B moves, zero converts.
    // 16 lanes cover one 256B row; 8 rows/thread.
    {
        const int rlane = tid & 15;
        const int row0  = tid >> 4;      // 0..15
        int idxs[8];
        #pragma unroll
        for (int it = 0; it < 8; ++it) {
            int rr = row0 + it * 16;     // 0..127
            int e  = rr & 63, sg = rr >> 6;
            idxs[it] = eidx[(sg ? N_EDGES : 0) + eb + e];
        }
        #pragma unroll
        for (int it = 0; it < 8; ++it) {
            int rr = row0 + it * 16;
            int e  = rr & 63, sg = rr >> 6;
            bf16x8 v = *(const bf16x8*)&hbf[(size_t)idxs[it] * H + rlane * 8];
            *(bf16x8*)&s_u.ein[e][sg * 128 + rlane * 8] = v;
        }
    }
    __syncthreads();   // barrier 1

    const int lane = tid & 63;
    const int q    = lane >> 4;
    const int l15  = lane & 15;
    const int n0   = (tid >> 6) * 32;
    const int w    = tid >> 6;

    // ---------------- GEMM1: [64x257] @ We1^T ----------------
    f32x4 acc[4][2] = {};
    #pragma unroll
    for (int ks = 0; ks < 8; ++ks) {
        int k0 = ks * 32 + q * 8;
        bf16x8 a0 = *(const bf16x8*)&s_u.ein[l15][k0];
        bf16x8 a1 = *(const bf16x8*)&s_u.ein[16 + l15][k0];
        bf16x8 a2 = *(const bf16x8*)&s_u.ein[32 + l15][k0];
        bf16x8 a3 = *(const bf16x8*)&s_u.ein[48 + l15][k0];
        bf16x8 b0 = *(const bf16x8*)&W1b[(n0 + l15) * 264 + k0];
        bf16x8 b1 = *(const bf16x8*)&W1b[(n0 + 16 + l15) * 264 + k0];
        acc[0][0] = __builtin_amdgcn_mfma_f32_16x16x32_bf16(a0, b0, acc[0][0], 0, 0, 0);
        acc[0][1] = __builtin_amdgcn_mfma_f32_16x16x32_bf16(a0, b1, acc[0][1], 0, 0, 0);
        acc[1][0] = __builtin_amdgcn_mfma_f32_16x16x32_bf16(a1, b0, acc[1][0], 0, 0, 0);
        acc[1][1] = __builtin_amdgcn_mfma_f32_16x16x32_bf16(a1, b1, acc[1][1], 0, 0, 0);
        acc[2][0] = __builtin_amdgcn_mfma_f32_16x16x32_bf16(a2, b0, acc[2][0], 0, 0, 0);
        acc[2][1] = __builtin_amdgcn_mfma_f32_16x16x32_bf16(a2, b1, acc[2][1], 0, 0, 0);
        acc[3][0] = __builtin_amdgcn_mfma_f32_16x16x32_bf16(a3, b0, acc[3][0], 0, 0, 0);
        acc[3][1] = __builtin_amdgcn_mfma_f32_16x16x32_bf16(a3, b1, acc[3][1], 0, 0, 0);
    }
    #pragma unroll
    for (int ct = 0; ct < 2; ++ct) {
        int col = n0 + ct * 16 + l15;
        float w256 = We1f[col * EIN + 256];   // rank-1 fixup for odd K
        float bias = be1[col];
        #pragma unroll
        for (int rt = 0; rt < 4; ++rt) {
            #pragma unroll
            for (int r = 0; r < 4; ++r) {
                int row = rt * 16 + q * 4 + r;
                float v = acc[rt][ct][r] + s_rn[row] * w256 + bias;
                s_t[row][col] = f2bfr(silu(v));
            }
        }
    }
    __syncthreads();   // barrier 2

    // ---------------- GEMM2: t1 @ We2^T -> m ----------------
    f32x4 acc2[4][2] = {};
    #pragma unroll
    for (int ks = 0; ks < 4; ++ks) {
        int k0 = ks * 32 + q * 8;
        bf16x8 a0 = *(const bf16x8*)&s_t[l15][k0];
        bf16x8 a1 = *(const bf16x8*)&s_t[16 + l15][k0];
        bf16x8 a2 = *(const bf16x8*)&s_t[32 + l15][k0];
        bf16x8 a3 = *(const bf16x8*)&s_t[48 + l15][k0];
        bf16x8 b0 = *(const bf16x8*)&W2b[(n0 + l15) * 128 + k0];
        bf16x8 b1 = *(const bf16x8*)&W2b[(n0 + 16 + l15) * 128 + k0];
        acc2[0][0] = __builtin_amdgcn_mfma_f32_16x16x32_bf16(a0, b0, acc2[0][0], 0, 0, 0);
        acc2[0][1] = __builtin_amdgcn_mfma_f32_16x16x32_bf16(a0, b1, acc2[0][1], 0, 0, 0);
        acc2[1][0] = __builtin_amdgcn_mfma_f32_16x16x32_bf16(a1, b0, acc2[1][0], 0, 0, 0);
        acc2[1][1] = __builtin_amdgcn_mfma_f32_16x16x32_bf16(a1, b1, acc2[1][1], 0, 0, 0);
        acc2[2][0] = __builtin_amdgcn_mfma_f32_16x16x32_bf16(a2, b0, acc2[2][0], 0, 0, 0);
        acc2[2][1] = __builtin_amdgcn_mfma_f32_16x16x32_bf16(a2, b1, acc2[2][1], 0, 0, 0);
        acc2[3][0] = __builtin_amdgcn_mfma_f32_16x16x32_bf16(a3, b0, acc2[3][0], 0, 0, 0);
        acc2[3][1] = __builtin_amdgcn_mfma_f32_16x16x32_bf16(a3, b1, acc2[3][1], 0, 0, 0);
    }
    #pragma unroll
    for (int ct = 0; ct < 2; ++ct) {
        int col = n0 + ct * 16 + l15;
        float bias = be2[col];
        #pragma unroll
        for (int rt = 0; rt < 4; ++rt) {
            #pragma unroll
            for (int r = 0; r < 4; ++r) {
                int row = rt * 16 + q * 4 + r;
                s_u.m[row][col] = f2bfr(acc2[rt][ct][r] + bias);
            }
        }
    }
    __syncthreads();   // barrier 3

    // ---- agg atomics: wave-per-row, coalesced, fire-and-forget ----
    #pragma unroll
    for (int i = 0; i < 16; ++i) {
        int row = w + i * 4;
        unsigned pr = *(const unsigned*)&s_u.m[row][lane * 2];
        if constexpr (AGGBF16) {
            pk_agg_add(&aggb[(size_t)s_row[row] * 64 + lane], pr);
        } else {
            float f0 = __builtin_bit_cast(float, pr << 16);
            float f1 = __builtin_bit_cast(float, pr & 0xFFFF0000u);
            float* dst = &aggf[(size_t)s_row[row] * H + 2 * lane];
            atomicAdd(dst, f0);
            atomicAdd(dst + 1, f1);
        }
    }

    // ---------------- GEMM3: m @ Wc1^T, dot wc2 ----------------
    f32x4 acc3[4][2] = {};
    #pragma unroll
    for (int ks = 0; ks < 4; ++ks) {
        int k0 = ks * 32 + q * 8;
        bf16x8 a0 = *(const bf16x8*)&s_u.m[l15][k0];
        bf16x8 a1 = *(const bf16x8*)&s_u.m[16 + l15][k0];
        bf16x8 a2 = *(const bf16x8*)&s_u.m[32 + l15][k0];
        bf16x8 a3 = *(const bf16x8*)&s_u.m[48 + l15][k0];
        bf16x8 b0 = *(const bf16x8*)&Wc1b[(n0 + l15) * 128 + k0];
        bf16x8 b1 = *(const bf16x8*)&Wc1b[(n0 + 16 + l15) * 128 + k0];
        acc3[0][0] = __builtin_amdgcn_mfma_f32_16x16x32_bf16(a0, b0, acc3[0][0], 0, 0, 0);
        acc3[0][1] = __builtin_amdgcn_mfma_f32_16x16x32_bf16(a0, b1, acc3[0][1], 0, 0, 0);
        acc3[1][0] = __builtin_amdgcn_mfma_f32_16x16x32_bf16(a1, b0, acc3[1][0], 0, 0, 0);
        acc3[1][1] = __builtin_amdgcn_mfma_f32_16x16x32_bf16(a1, b1, acc3[1][1], 0, 0, 0);
        acc3[2][0] = __builtin_amdgcn_mfma_f32_16x16x32_bf16(a2, b0, acc3[2][0], 0, 0, 0);
        acc3[2][1] = __builtin_amdgcn_mfma_f32_16x16x32_bf16(a2, b1, acc3[2][1], 0, 0, 0);
        acc3[3][0] = __builtin_amdgcn_mfma_f32_16x16x32_bf16(a3, b0, acc3[3][0], 0, 0, 0);
        acc3[3][1] = __builtin_amdgcn_mfma_f32_16x16x32_bf16(a3, b1, acc3[3][1], 0, 0, 0);
    }
    float p[4][4] = {};
    #pragma unroll
    for (int ct = 0; ct < 2; ++ct) {
        int col = n0 + ct * 16 + l15;
        float bias = bc1[col];
        float w2 = wc2f[col];
        #pragma unroll
        for (int rt = 0; rt < 4; ++rt) {
            #pragma unroll
            for (int r = 0; r < 4; ++r)
                p[rt][r] += silu(acc3[rt][ct][r] + bias) * w2;
        }
    }
    #pragma unroll
    for (int rt = 0; rt < 4; ++rt) {
        #pragma unroll
        for (int r = 0; r < 4; ++r) {
            float v = p[rt][r];
            v += __shfl_xor(v, 1);
            v += __shfl_xor(v, 2);
            v += __shfl_xor(v, 4);
            v += __shfl_xor(v, 8);
            if (l15 == 0) atomicAdd(&s_dot[rt * 16 + q * 4 + r], v);
        }
    }
    __syncthreads();   // barrier 4

    if (tid < EPB) {
        float s = tanhf(s_dot[tid] + bc2[0]) * 0.1f;
        int r = s_row[tid];
        atomicAdd(&pos_out[r * 3 + 0], s * s_unit[tid][0]);
        atomicAdd(&pos_out[r * 3 + 1], s * s_unit[tid][1]);
        atomicAdd(&pos_out[r * 3 + 2], s * s_unit[tid][2]);
    }
}

// ---- node kernel: 32 nodes / block ----
template<bool AGGBF16>
__global__ __launch_bounds__(256) void node_kernel(
    const float* __restrict__ h, const short* __restrict__ hbf,
    const unsigned short* __restrict__ aggb, const float* __restrict__ aggf,
    const float* __restrict__ bn1, const float* __restrict__ bn2,
    const short* __restrict__ Wn1b, const short* __restrict__ Wn2b,
    float* __restrict__ hout)
{
    __shared__ short s_a[32][264];
    __shared__ short s_t[32][136];

    const int tid = threadIdx.x;
    const int nb  = blockIdx.x * 32;

    // [hbf | agg] -> s_a; 16 lanes per 256B row, 4 rows/thread
    {
        const int rlane = tid & 15;
        const int row0  = tid >> 4;
        #pragma unroll
        for (int it = 0; it < 4; ++it) {
            int rr = row0 + it * 16;     // 0..63
            int e  = rr & 31, sg = rr >> 5;
            int node = nb + e;
            if (node >= N_NODES) node = N_NODES - 1;
            bf16x8 v;
            if (sg == 0) {
                v = *(const bf16x8*)&hbf[(size_t)node * H + rlane * 8];
            } else if constexpr (AGGBF16) {
                v = *(const bf16x8*)&aggb[(size_t)node * H + rlane * 8];
            } else {
                const float* src = &aggf[(size_t)node * H + rlane * 8];
                bf16x8 t;
                #pragma unroll
                for (int j = 0; j < 8; ++j) t[j] = f2bfr(src[j]);
                v = t;
            }
            *(bf16x8*)&s_a[e][sg * 128 + rlane * 8] = v;
        }
    }
    __syncthreads();

    const int lane = tid & 63;
    const int q    = lane >> 4;
    const int l15  = lane & 15;
    const int n0   = (tid >> 6) * 32;

    f32x4 acc[2][2] = {};
    #pragma unroll
    for (int ks = 0; ks < 8; ++ks) {
        int k0 = ks * 32 + q * 8;
        bf16x8 a0 = *(const bf16x8*)&s_a[l15][k0];
        bf16x8 a1 = *(const bf16x8*)&s_a[16 + l15][k0];
        bf16x8 b0 = *(const bf16x8*)&Wn1b[(n0 + l15) * 264 + k0];
        bf16x8 b1 = *(const bf16x8*)&Wn1b[(n0 + 16 + l15) * 264 + k0];
        acc[0][0] = __builtin_amdgcn_mfma_f32_16x16x32_bf16(a0, b0, acc[0][0], 0, 0, 0);
        acc[0][1] = __builtin_amdgcn_mfma_f32_16x16x32_bf16(a0, b1, acc[0][1], 0, 0, 0);
        acc[1][0] = __builtin_amdgcn_mfma_f32_16x16x32_bf16(a1, b0, acc[1][0], 0, 0, 0);
        acc[1][1] = __builtin_amdgcn_mfma_f32_16x16x32_bf16(a1, b1, acc[1][1], 0, 0, 0);
    }
    #pragma unroll
    for (int ct = 0; ct < 2; ++ct) {
        int col = n0 + ct * 16 + l15;
        float bias = bn1[col];
        #pragma unroll
        for (int rt = 0; rt < 2; ++rt) {
            #pragma unroll
            for (int r = 0; r < 4; ++r) {
                int row = rt * 16 + q * 4 + r;
                s_t[row][col] = f2bfr(silu(acc[rt][ct][r] + bias));
            }
        }
    }
    __syncthreads();

    f32x4 acc2[2][2] = {};
    #pragma unroll
    for (int ks = 0; ks < 4; ++ks) {
        int k0 = ks * 32 + q * 8;
        bf16x8 a0 = *(const bf16x8*)&s_t[l15][k0];
        bf16x8 a1 = *(const bf16x8*)&s_t[16 + l15][k0];
        bf16x8 b0 = *(const bf16x8*)&Wn2b[(n0 + l15) * 128 + k0];
        bf16x8 b1 = *(const bf16x8*)&Wn2b[(n0 + 16 + l15) * 128 + k0];
        acc2[0][0] = __builtin_amdgcn_mfma_f32_16x16x32_bf16(a0, b0, acc2[0][0], 0, 0, 0);
        acc2[0][1] = __builtin_amdgcn_mfma_f32_16x16x32_bf16(a0, b1, acc2[0][1], 0, 0, 0);
        acc2[1][0] = __builtin_amdgcn_mfma_f32_16x16x32_bf16(a1, b0, acc2[1][0], 0, 0, 0);
        acc2[1][1] = __builtin_amdgcn_mfma_f32_16x16x32_bf16(a1, b1, acc2[1][1], 0, 0, 0);
    }
    #pragma unroll
    for (int ct = 0; ct < 2; ++ct) {
        int col = n0 + ct * 16 + l15;
        float bias = bn2[col];
        #pragma unroll
        for (int rt = 0; rt < 2; ++rt) {
            #pragma unroll
            for (int r = 0; r < 4; ++r) {
                int row = rt * 16 + q * 4 + r;
                int nrow = nb + row;
                if (nrow < N_NODES) {
                    float v = acc2[rt][ct][r] + bias + h[(size_t)nrow * H + col];
                    hout[(size_t)nrow * H + col] = v;
                }
            }
        }
    }
}

extern "C" void kernel_launch(void* const* d_in, const int* in_sizes, int n_in,
                              void* d_out, int out_size, void* d_ws, size_t ws_size,
                              hipStream_t stream) {
    const float* h   = (const float*)d_in[0];
    const float* pos = (const float*)d_in[1];
    const int*  eidx = (const int*)d_in[2];
    const float* We1 = (const float*)d_in[3];
    const float* be1 = (const float*)d_in[4];
    const float* We2 = (const float*)d_in[5];
    const float* be2 = (const float*)d_in[6];
    const float* Wn1 = (const float*)d_in[7];
    const float* bn1 = (const float*)d_in[8];
    const float* Wn2 = (const float*)d_in[9];
    const float* bn2 = (const float*)d_in[10];
    const float* Wc1 = (const float*)d_in[11];
    const float* bc1 = (const float*)d_in[12];
    const float* Wc2 = (const float*)d_in[13];
    const float* bc2 = (const float*)d_in[14];

    float* out_h   = (float*)d_out;
    float* out_pos = out_h + (size_t)N_NODES * H;

    char* ws = (char*)d_ws;
    short* W1b  = (short*)(ws);
    short* W2b  = (short*)(ws + 2 * P_W1);
    short* Wc1b = (short*)(ws + 2 * (P_W1 + P_W2));
    short* Wn1b = (short*)(ws + 2 * (P_W1 + 2 * P_W2));
    short* Wn2b = (short*)(ws + 2 * (2 * P_W1 + 2 * P_W2));
    const size_t WSW = 2 * (size_t)(2 * P_W1 + 3 * P_W2);   // 233472 B
    const size_t HBF = (size_t)N_NODES * H * 2;             // 12.8 MB
    const size_t AGG = (size_t)N_NODES * H * 2;             // 12.8 MB
    short* hbf = (short*)(ws + WSW);
    const bool use_bf16 = (ws_size >= WSW + HBF + AGG);

    hipMemcpyAsync(out_pos, pos, (size_t)N_NODES * 3 * sizeof(float),
                   hipMemcpyDeviceToDevice, stream);
    prep_all<<<(NH4 + P_TOT + 255) / 256, 256, 0, stream>>>(
        h, We1, We2, Wc1, Wn1, Wn2, hbf, W1b, W2b, Wc1b, Wn1b, Wn2b);

    if (use_bf16) {
        unsigned* aggb = (unsigned*)(ws + WSW + HBF);
        hipMemsetAsync(aggb, 0, AGG, stream);   // 0x0000 == bf16 +0.0
        edge_kernel<true><<<N_EDGES / EPB, 256, 0, stream>>>(
            hbf, pos, eidx, We1, be1, be2, bc1, Wc2, bc2,
            W1b, W2b, Wc1b, aggb, nullptr, out_pos);
        node_kernel<true><<<(N_NODES + 31) / 32, 256, 0, stream>>>(
            h, hbf, (const unsigned short*)aggb, nullptr,
            bn1, bn2, Wn1b, Wn2b, out_h);
    } else {
        // fallback: f32 agg in d_out h region (requires ws >= WSW+HBF,
        // proven available: round-3 tier needed WSW+AGG of same size)
        hipMemsetAsync(out_h, 0, (size_t)N_NODES * H * sizeof(float), stream);
        edge_kernel<false><<<N_EDGES / EPB, 256, 0, stream>>>(
            hbf, pos, eidx, We1, be1, be2, bc1, Wc2, bc2,
            W1b, W2b, Wc1b, nullptr, out_h, out_pos);
        node_kernel<false><<<(N_NODES + 31) / 32, 256, 0, stream>>>(
            h, hbf, nullptr, out_h, bn1, bn2, Wn1b, Wn2b, out_h);
    }
}

// Round 5
// 443.716 us; speedup vs baseline: 12.5728x; 1.0478x over previous
//
#include <hip/hip_runtime.h>
#include <math.h>

#define N_NODES 50000
#define N_EDGES 800000
#define H 128
#define EIN 257
#define EPB 64   // edges per block

typedef short bf16x8 __attribute__((ext_vector_type(8)));
typedef short bf16x4 __attribute__((ext_vector_type(4)));
typedef short bf16x2 __attribute__((ext_vector_type(2)));
typedef float f32x4 __attribute__((ext_vector_type(4)));

// round-to-nearest-even f32 -> bf16 (one-time prep conversions)
static __device__ __forceinline__ short f2bf(float x) {
    unsigned u = __builtin_bit_cast(unsigned, x);
    unsigned r = (u + 0x7FFFu + ((u >> 16) & 1u)) >> 16;
    return (short)r;
}

// cheap round-half-up f32 -> bf16 (2 VALU insts)
static __device__ __forceinline__ short f2bfr(float x) {
    return (short)((__builtin_bit_cast(unsigned, x) + 0x8000u) >> 16);
}

// fast silu
static __device__ __forceinline__ float silu(float x) {
#if __has_builtin(__builtin_amdgcn_rcpf)
    return x * __builtin_amdgcn_rcpf(1.0f + __expf(-x));
#else
    return x / (1.0f + __expf(-x));
#endif
}

// packed bf16 atomic add
static __device__ __forceinline__ void pk_agg_add(unsigned* addr, unsigned val) {
#if __has_builtin(__builtin_amdgcn_global_atomic_fadd_v2bf16)
    bf16x2 v = __builtin_bit_cast(bf16x2, val);
    (void)__builtin_amdgcn_global_atomic_fadd_v2bf16(
        (__attribute__((address_space(1))) bf16x2*)(unsigned long long)addr, v);
#else
    asm volatile("global_atomic_pk_add_bf16 %0, %1, off"
                 :: "v"(addr), "v"(val) : "memory");
#endif
}

// ---- prep: h->bf16, weights->bf16 (padded), agg zero, pos copy ----
#define P_W1  (128*264)
#define P_W2  (128*128)
#define P_TOT (P_W1 + P_W2 + P_W2 + P_W1 + P_W2)
#define NH4   (N_NODES * H / 4)          // h float4 count = 1,600,000
#define AGG16 (N_NODES * H * 2 / 16)     // agg bf16 bytes / 16 = 800,000
#define POS4  ((N_NODES * 3 + 3) / 4)    // pos float4 count (150000/4=37500)

__global__ __launch_bounds__(256) void prep_all(
    const float* __restrict__ hf,
    const float* __restrict__ We1, const float* __restrict__ We2,
    const float* __restrict__ Wc1, const float* __restrict__ Wn1,
    const float* __restrict__ Wn2,
    short* __restrict__ hbf,
    short* __restrict__ W1b, short* __restrict__ W2b, short* __restrict__ Wc1b,
    short* __restrict__ Wn1b, short* __restrict__ Wn2b,
    uint4* __restrict__ aggz, int aggz_n,          // zero-fill region (16B units)
    float4* __restrict__ pos_dst, const float4* __restrict__ pos_src)
{
    int i = blockIdx.x * 256 + threadIdx.x;
    if (i < NH4) {
        float4 v = ((const float4*)hf)[i];
        bf16x4 s4 = { f2bf(v.x), f2bf(v.y), f2bf(v.z), f2bf(v.w) };
        *(bf16x4*)&hbf[i * 4] = s4;
        return;
    }
    i -= NH4;
    if (i < P_TOT) {
        if (i < P_W1) {
            int j = i / 264, k = i % 264;
            W1b[i] = (k < EIN) ? f2bf(We1[j * EIN + k]) : (short)0;
        } else if (i < P_W1 + P_W2) {
            int t = i - P_W1;
            W2b[t] = f2bf(We2[t]);
        } else if (i < P_W1 + 2 * P_W2) {
            int t = i - P_W1 - P_W2;
            Wc1b[t] = f2bf(Wc1[t]);
        } else if (i < P_W1 + 2 * P_W2 + P_W1) {
            int t = i - P_W1 - 2 * P_W2;
            int j = t / 264, k = t % 264;
            Wn1b[t] = (k < 256) ? f2bf(Wn1[j * 256 + k]) : (short)0;
        } else {
            int t = i - 2 * P_W1 - 2 * P_W2;
            Wn2b[t] = f2bf(Wn2[t]);
        }
        return;
    }
    i -= P_TOT;
    if (i < aggz_n) {                    // bf16 +0.0 == 0x0000
        aggz[i] = uint4{0u, 0u, 0u, 0u};
        return;
    }
    i -= aggz_n;
    if (i < POS4) pos_dst[i] = pos_src[i];
}

// ---- edge kernel: 64 edges / block, 256 threads (4 waves) ----
// LDS union overlays t/m onto the dead ein buffer -> 36.4 KB -> 4 blocks/CU.
template<bool AGGBF16>
__global__ __launch_bounds__(256, 4) void edge_kernel(
    const short* __restrict__ hbf, const float* __restrict__ pos,
    const int* __restrict__ eidx,
    const float* __restrict__ We1f, const float* __restrict__ be1,
    const float* __restrict__ be2, const float* __restrict__ bc1,
    const float* __restrict__ wc2f, const float* __restrict__ bc2,
    const short* __restrict__ W1b, const short* __restrict__ W2b,
    const short* __restrict__ Wc1b,
    unsigned* __restrict__ aggb,   // bf16 agg, 64 dwords/row
    float* __restrict__ aggf,      // f32 agg (fallback)
    float* __restrict__ pos_out)
{
    __shared__ union {
        short ein[EPB][264];                               // 33792 B (phase A)
        struct { short t[EPB][136]; short m[EPB][136]; } p; // 34816 B (phase B)
    } s_u;
    __shared__ float s_rn[EPB];
    __shared__ float s_unit[EPB][3];
    __shared__ int   s_row[EPB];
    __shared__ float s_dot[EPB];

    const int tid = threadIdx.x;
    const int eb  = blockIdx.x * EPB;

    if (tid < EPB) {
        int ge = eb + tid;
        int r = eidx[ge];
        int c = eidx[N_EDGES + ge];
        s_row[tid] = r;
        float dx = pos[r*3+0] - pos[c*3+0];
        float dy = pos[r*3+1] - pos[c*3+1];
        float dz = pos[r*3+2] - pos[c*3+2];
        float nrm = sqrtf(dx*dx + dy*dy + dz*dz);
        float rn  = fmaxf(nrm, 1e-8f);
        s_rn[tid] = rn;
        s_unit[tid][0] = dx / rn;
        s_unit[tid][1] = dy / rn;
        s_unit[tid][2] = dz / rn;
        s_dot[tid] = 0.0f;
    }

    // gather hbf[row]|hbf[col] -> s_ein: pure bf16 16B moves.
    {
        const int rlane = tid & 15;
        const int row0  = tid >> 4;      // 0..15
        int idxs[8];
        #pragma unroll
        for (int it = 0; it < 8; ++it) {
            int rr = row0 + it * 16;     // 0..127
            int e  = rr & 63, sg = rr >> 6;
            idxs[it] = eidx[(sg ? N_EDGES : 0) + eb + e];
        }
        #pragma unroll
        for (int it = 0; it < 8; ++it) {
            int rr = row0 + it * 16;
            int e  = rr & 63, sg = rr >> 6;
            bf16x8 v = *(const bf16x8*)&hbf[(size_t)idxs[it] * H + rlane * 8];
            *(bf16x8*)&s_u.ein[e][sg * 128 + rlane * 8] = v;
        }
    }
    __syncthreads();   // barrier 1: ein ready

    const int lane = tid & 63;
    const int q    = lane >> 4;
    const int l15  = lane & 15;
    const int n0   = (tid >> 6) * 32;
    const int w    = tid >> 6;

    // ---------------- GEMM1: [64x257] @ We1^T ----------------
    f32x4 acc[4][2] = {};
    #pragma unroll
    for (int ks = 0; ks < 8; ++ks) {
        int k0 = ks * 32 + q * 8;
        bf16x8 a0 = *(const bf16x8*)&s_u.ein[l15][k0];
        bf16x8 a1 = *(const bf16x8*)&s_u.ein[16 + l15][k0];
        bf16x8 a2 = *(const bf16x8*)&s_u.ein[32 + l15][k0];
        bf16x8 a3 = *(const bf16x8*)&s_u.ein[48 + l15][k0];
        bf16x8 b0 = *(const bf16x8*)&W1b[(n0 + l15) * 264 + k0];
        bf16x8 b1 = *(const bf16x8*)&W1b[(n0 + 16 + l15) * 264 + k0];
        acc[0][0] = __builtin_amdgcn_mfma_f32_16x16x32_bf16(a0, b0, acc[0][0], 0, 0, 0);
        acc[0][1] = __builtin_amdgcn_mfma_f32_16x16x32_bf16(a0, b1, acc[0][1], 0, 0, 0);
        acc[1][0] = __builtin_amdgcn_mfma_f32_16x16x32_bf16(a1, b0, acc[1][0], 0, 0, 0);
        acc[1][1] = __builtin_amdgcn_mfma_f32_16x16x32_bf16(a1, b1, acc[1][1], 0, 0, 0);
        acc[2][0] = __builtin_amdgcn_mfma_f32_16x16x32_bf16(a2, b0, acc[2][0], 0, 0, 0);
        acc[2][1] = __builtin_amdgcn_mfma_f32_16x16x32_bf16(a2, b1, acc[2][1], 0, 0, 0);
        acc[3][0] = __builtin_amdgcn_mfma_f32_16x16x32_bf16(a3, b0, acc[3][0], 0, 0, 0);
        acc[3][1] = __builtin_amdgcn_mfma_f32_16x16x32_bf16(a3, b1, acc[3][1], 0, 0, 0);
    }
    // epilogue 1 into registers (ein still live until barrier 2)
    short tv[2][4][4];
    #pragma unroll
    for (int ct = 0; ct < 2; ++ct) {
        int col = n0 + ct * 16 + l15;
        float w256 = We1f[col * EIN + 256];   // rank-1 fixup for odd K
        float bias = be1[col];
        #pragma unroll
        for (int rt = 0; rt < 4; ++rt) {
            #pragma unroll
            for (int r = 0; r < 4; ++r) {
                int row = rt * 16 + q * 4 + r;
                tv[ct][rt][r] = f2bfr(silu(acc[rt][ct][r] + s_rn[row] * w256 + bias));
            }
        }
    }
    __syncthreads();   // barrier 2: all MFMA reads of ein done -> t may overlay
    #pragma unroll
    for (int ct = 0; ct < 2; ++ct) {
        int col = n0 + ct * 16 + l15;
        #pragma unroll
        for (int rt = 0; rt < 4; ++rt)
            #pragma unroll
            for (int r = 0; r < 4; ++r)
                s_u.p.t[rt * 16 + q * 4 + r][col] = tv[ct][rt][r];
    }
    __syncthreads();   // barrier 3: t ready

    // ---------------- GEMM2: t1 @ We2^T -> m ----------------
    f32x4 acc2[4][2] = {};
    #pragma unroll
    for (int ks = 0; ks < 4; ++ks) {
        int k0 = ks * 32 + q * 8;
        bf16x8 a0 = *(const bf16x8*)&s_u.p.t[l15][k0];
        bf16x8 a1 = *(const bf16x8*)&s_u.p.t[16 + l15][k0];
        bf16x8 a2 = *(const bf16x8*)&s_u.p.t[32 + l15][k0];
        bf16x8 a3 = *(const bf16x8*)&s_u.p.t[48 + l15][k0];
        bf16x8 b0 = *(const bf16x8*)&W2b[(n0 + l15) * 128 + k0];
        bf16x8 b1 = *(const bf16x8*)&W2b[(n0 + 16 + l15) * 128 + k0];
        acc2[0][0] = __builtin_amdgcn_mfma_f32_16x16x32_bf16(a0, b0, acc2[0][0], 0, 0, 0);
        acc2[0][1] = __builtin_amdgcn_mfma_f32_16x16x32_bf16(a0, b1, acc2[0][1], 0, 0, 0);
        acc2[1][0] = __builtin_amdgcn_mfma_f32_16x16x32_bf16(a1, b0, acc2[1][0], 0, 0, 0);
        acc2[1][1] = __builtin_amdgcn_mfma_f32_16x16x32_bf16(a1, b1, acc2[1][1], 0, 0, 0);
        acc2[2][0] = __builtin_amdgcn_mfma_f32_16x16x32_bf16(a2, b0, acc2[2][0], 0, 0, 0);
        acc2[2][1] = __builtin_amdgcn_mfma_f32_16x16x32_bf16(a2, b1, acc2[2][1], 0, 0, 0);
        acc2[3][0] = __builtin_amdgcn_mfma_f32_16x16x32_bf16(a3, b0, acc2[3][0], 0, 0, 0);
        acc2[3][1] = __builtin_amdgcn_mfma_f32_16x16x32_bf16(a3, b1, acc2[3][1], 0, 0, 0);
    }
    // epilogue 2 writes m region (disjoint from t region; no barrier needed)
    #pragma unroll
    for (int ct = 0; ct < 2; ++ct) {
        int col = n0 + ct * 16 + l15;
        float bias = be2[col];
        #pragma unroll
        for (int rt = 0; rt < 4; ++rt) {
            #pragma unroll
            for (int r = 0; r < 4; ++r) {
                int row = rt * 16 + q * 4 + r;
                s_u.p.m[row][col] = f2bfr(acc2[rt][ct][r] + bias);
            }
        }
    }
    __syncthreads();   // barrier 4: m ready

    // ---- agg atomics: wave-per-row, coalesced, fire-and-forget ----
    #pragma unroll
    for (int i = 0; i < 16; ++i) {
        int row = w + i * 4;
        unsigned pr = *(const unsigned*)&s_u.p.m[row][lane * 2];
        if constexpr (AGGBF16) {
            pk_agg_add(&aggb[(size_t)s_row[row] * 64 + lane], pr);
        } else {
            float f0 = __builtin_bit_cast(float, pr << 16);
            float f1 = __builtin_bit_cast(float, pr & 0xFFFF0000u);
            float* dst = &aggf[(size_t)s_row[row] * H + 2 * lane];
            atomicAdd(dst, f0);
            atomicAdd(dst + 1, f1);
        }
    }

    // ---------------- GEMM3: m @ Wc1^T, dot wc2 ----------------
    f32x4 acc3[4][2] = {};
    #pragma unroll
    for (int ks = 0; ks < 4; ++ks) {
        int k0 = ks * 32 + q * 8;
        bf16x8 a0 = *(const bf16x8*)&s_u.p.m[l15][k0];
        bf16x8 a1 = *(const bf16x8*)&s_u.p.m[16 + l15][k0];
        bf16x8 a2 = *(const bf16x8*)&s_u.p.m[32 + l15][k0];
        bf16x8 a3 = *(const bf16x8*)&s_u.p.m[48 + l15][k0];
        bf16x8 b0 = *(const bf16x8*)&Wc1b[(n0 + l15) * 128 + k0];
        bf16x8 b1 = *(const bf16x8*)&Wc1b[(n0 + 16 + l15) * 128 + k0];
        acc3[0][0] = __builtin_amdgcn_mfma_f32_16x16x32_bf16(a0, b0, acc3[0][0], 0, 0, 0);
        acc3[0][1] = __builtin_amdgcn_mfma_f32_16x16x32_bf16(a0, b1, acc3[0][1], 0, 0, 0);
        acc3[1][0] = __builtin_amdgcn_mfma_f32_16x16x32_bf16(a1, b0, acc3[1][0], 0, 0, 0);
        acc3[1][1] = __builtin_amdgcn_mfma_f32_16x16x32_bf16(a1, b1, acc3[1][1], 0, 0, 0);
        acc3[2][0] = __builtin_amdgcn_mfma_f32_16x16x32_bf16(a2, b0, acc3[2][0], 0, 0, 0);
        acc3[2][1] = __builtin_amdgcn_mfma_f32_16x16x32_bf16(a2, b1, acc3[2][1], 0, 0, 0);
        acc3[3][0] = __builtin_amdgcn_mfma_f32_16x16x32_bf16(a3, b0, acc3[3][0], 0, 0, 0);
        acc3[3][1] = __builtin_amdgcn_mfma_f32_16x16x32_bf16(a3, b1, acc3[3][1], 0, 0, 0);
    }
    float p[4][4] = {};
    #pragma unroll
    for (int ct = 0; ct < 2; ++ct) {
        int col = n0 + ct * 16 + l15;
        float bias = bc1[col];
        float w2 = wc2f[col];
        #pragma unroll
        for (int rt = 0; rt < 4; ++rt) {
            #pragma unroll
            for (int r = 0; r < 4; ++r)
                p[rt][r] += silu(acc3[rt][ct][r] + bias) * w2;
        }
    }
    #pragma unroll
    for (int rt = 0; rt < 4; ++rt) {
        #pragma unroll
        for (int r = 0; r < 4; ++r) {
            float v = p[rt][r];
            v += __shfl_xor(v, 1);
            v += __shfl_xor(v, 2);
            v += __shfl_xor(v, 4);
            v += __shfl_xor(v, 8);
            if (l15 == 0) atomicAdd(&s_dot[rt * 16 + q * 4 + r], v);
        }
    }
    __syncthreads();   // barrier 5

    if (tid < EPB) {
        float s = tanhf(s_dot[tid] + bc2[0]) * 0.1f;
        int r = s_row[tid];
        atomicAdd(&pos_out[r * 3 + 0], s * s_unit[tid][0]);
        atomicAdd(&pos_out[r * 3 + 1], s * s_unit[tid][1]);
        atomicAdd(&pos_out[r * 3 + 2], s * s_unit[tid][2]);
    }
}

// ---- node kernel: 32 nodes / block ----
template<bool AGGBF16>
__global__ __launch_bounds__(256) void node_kernel(
    const float* __restrict__ h, const short* __restrict__ hbf,
    const unsigned short* __restrict__ aggb, const float* __restrict__ aggf,
    const float* __restrict__ bn1, const float* __restrict__ bn2,
    const short* __restrict__ Wn1b, const short* __restrict__ Wn2b,
    float* __restrict__ hout)
{
    __shared__ short s_a[32][264];
    __shared__ short s_t[32][136];

    const int tid = threadIdx.x;
    const int nb  = blockIdx.x * 32;

    {
        const int rlane = tid & 15;
        const int row0  = tid >> 4;
        #pragma unroll
        for (int it = 0; it < 4; ++it) {
            int rr = row0 + it * 16;     // 0..63
            int e  = rr & 31, sg = rr >> 5;
            int node = nb + e;
            if (node >= N_NODES) node = N_NODES - 1;
            bf16x8 v;
            if (sg == 0) {
                v = *(const bf16x8*)&hbf[(size_t)node * H + rlane * 8];
            } else if constexpr (AGGBF16) {
                v = *(const bf16x8*)&aggb[(size_t)node * H + rlane * 8];
            } else {
                const float* src = &aggf[(size_t)node * H + rlane * 8];
                bf16x8 t;
                #pragma unroll
                for (int j = 0; j < 8; ++j) t[j] = f2bfr(src[j]);
                v = t;
            }
            *(bf16x8*)&s_a[e][sg * 128 + rlane * 8] = v;
        }
    }
    __syncthreads();

    const int lane = tid & 63;
    const int q    = lane >> 4;
    const int l15  = lane & 15;
    const int n0   = (tid >> 6) * 32;

    f32x4 acc[2][2] = {};
    #pragma unroll
    for (int ks = 0; ks < 8; ++ks) {
        int k0 = ks * 32 + q * 8;
        bf16x8 a0 = *(const bf16x8*)&s_a[l15][k0];
        bf16x8 a1 = *(const bf16x8*)&s_a[16 + l15][k0];
        bf16x8 b0 = *(const bf16x8*)&Wn1b[(n0 + l15) * 264 + k0];
        bf16x8 b1 = *(const bf16x8*)&Wn1b[(n0 + 16 + l15) * 264 + k0];
        acc[0][0] = __builtin_amdgcn_mfma_f32_16x16x32_bf16(a0, b0, acc[0][0], 0, 0, 0);
        acc[0][1] = __builtin_amdgcn_mfma_f32_16x16x32_bf16(a0, b1, acc[0][1], 0, 0, 0);
        acc[1][0] = __builtin_amdgcn_mfma_f32_16x16x32_bf16(a1, b0, acc[1][0], 0, 0, 0);
        acc[1][1] = __builtin_amdgcn_mfma_f32_16x16x32_bf16(a1, b1, acc[1][1], 0, 0, 0);
    }
    #pragma unroll
    for (int ct = 0; ct < 2; ++ct) {
        int col = n0 + ct * 16 + l15;
        float bias = bn1[col];
        #pragma unroll
        for (int rt = 0; rt < 2; ++rt) {
            #pragma unroll
            for (int r = 0; r < 4; ++r) {
                int row = rt * 16 + q * 4 + r;
                s_t[row][col] = f2bfr(silu(acc[rt][ct][r] + bias));
            }
        }
    }
    __syncthreads();

    f32x4 acc2[2][2] = {};
    #pragma unroll
    for (int ks = 0; ks < 4; ++ks) {
        int k0 = ks * 32 + q * 8;
        bf16x8 a0 = *(const bf16x8*)&s_t[l15][k0];
        bf16x8 a1 = *(const bf16x8*)&s_t[16 + l15][k0];
        bf16x8 b0 = *(const bf16x8*)&Wn2b[(n0 + l15) * 128 + k0];
        bf16x8 b1 = *(const bf16x8*)&Wn2b[(n0 + 16 + l15) * 128 + k0];
        acc2[0][0] = __builtin_amdgcn_mfma_f32_16x16x32_bf16(a0, b0, acc2[0][0], 0, 0, 0);
        acc2[0][1] = __builtin_amdgcn_mfma_f32_16x16x32_bf16(a0, b1, acc2[0][1], 0, 0, 0);
        acc2[1][0] = __builtin_amdgcn_mfma_f32_16x16x32_bf16(a1, b0, acc2[1][0], 0, 0, 0);
        acc2[1][1] = __builtin_amdgcn_mfma_f32_16x16x32_bf16(a1, b1, acc2[1][1], 0, 0, 0);
    }
    #pragma unroll
    for (int ct = 0; ct < 2; ++ct) {
        int col = n0 + ct * 16 + l15;
        float bias = bn2[col];
        #pragma unroll
        for (int rt = 0; rt < 2; ++rt) {
            #pragma unroll
            for (int r = 0; r < 4; ++r) {
                int row = rt * 16 + q * 4 + r;
                int nrow = nb + row;
                if (nrow < N_NODES) {
                    float v = acc2[rt][ct][r] + bias + h[(size_t)nrow * H + col];
                    hout[(size_t)nrow * H + col] = v;
                }
            }
        }
    }
}

extern "C" void kernel_launch(void* const* d_in, const int* in_sizes, int n_in,
                              void* d_out, int out_size, void* d_ws, size_t ws_size,
                              hipStream_t stream) {
    const float* h   = (const float*)d_in[0];
    const float* pos = (const float*)d_in[1];
    const int*  eidx = (const int*)d_in[2];
    const float* We1 = (const float*)d_in[3];
    const float* be1 = (const float*)d_in[4];
    const float* We2 = (const float*)d_in[5];
    const float* be2 = (const float*)d_in[6];
    const float* Wn1 = (const float*)d_in[7];
    const float* bn1 = (const float*)d_in[8];
    const float* Wn2 = (const float*)d_in[9];
    const float* bn2 = (const float*)d_in[10];
    const float* Wc1 = (const float*)d_in[11];
    const float* bc1 = (const float*)d_in[12];
    const float* Wc2 = (const float*)d_in[13];
    const float* bc2 = (const float*)d_in[14];

    float* out_h   = (float*)d_out;
    float* out_pos = out_h + (size_t)N_NODES * H;

    char* ws = (char*)d_ws;
    short* W1b  = (short*)(ws);
    short* W2b  = (short*)(ws + 2 * P_W1);
    short* Wc1b = (short*)(ws + 2 * (P_W1 + P_W2));
    short* Wn1b = (short*)(ws + 2 * (P_W1 + 2 * P_W2));
    short* Wn2b = (short*)(ws + 2 * (2 * P_W1 + 2 * P_W2));
    const size_t WSW = 2 * (size_t)(2 * P_W1 + 3 * P_W2);   // 233472 B
    const size_t HBF = (size_t)N_NODES * H * 2;             // 12.8 MB
    const size_t AGG = (size_t)N_NODES * H * 2;             // 12.8 MB
    short* hbf = (short*)(ws + WSW);
    const bool use_bf16 = (ws_size >= WSW + HBF + AGG);

    if (use_bf16) {
        unsigned* aggb = (unsigned*)(ws + WSW + HBF);
        const int prep_n = NH4 + P_TOT + AGG16 + POS4;
        prep_all<<<(prep_n + 255) / 256, 256, 0, stream>>>(
            h, We1, We2, Wc1, Wn1, Wn2, hbf, W1b, W2b, Wc1b, Wn1b, Wn2b,
            (uint4*)aggb, AGG16, (float4*)out_pos, (const float4*)pos);
        edge_kernel<true><<<N_EDGES / EPB, 256, 0, stream>>>(
            hbf, pos, eidx, We1, be1, be2, bc1, Wc2, bc2,
            W1b, W2b, Wc1b, aggb, nullptr, out_pos);
        node_kernel<true><<<(N_NODES + 31) / 32, 256, 0, stream>>>(
            h, hbf, (const unsigned short*)aggb, nullptr,
            bn1, bn2, Wn1b, Wn2b, out_h);
    } else {
        // fallback: f32 agg in d_out h region
        const int prep_n = NH4 + P_TOT + POS4;
        prep_all<<<(prep_n + 255) / 256, 256, 0, stream>>>(
            h, We1, We2, Wc1, Wn1, Wn2, hbf, W1b, W2b, Wc1b, Wn1b, Wn2b,
            nullptr, 0, (float4*)out_pos, (const float4*)pos);
        hipMemsetAsync(out_h, 0, (size_t)N_NODES * H * sizeof(float), stream);
        edge_kernel<false><<<N_EDGES / EPB, 256, 0, stream>>>(
            hbf, pos, eidx, We1, be1, be2, bc1, Wc2, bc2,
            W1b, W2b, Wc1b, nullptr, out_h, out_pos);
        node_kernel<false><<<(N_NODES + 31) / 32, 256, 0, stream>>>(
            h, hbf, nullptr, out_h, bn1, bn2, Wn1b, Wn2b, out_h);
    }
}